// Round 9
// baseline (31.476 us; speedup 1.0000x reference)
//
#include <hip/hip_runtime.h>

// CARAFE: x [4,256,64,64] f32, kernel [4,25,128,128] f32 -> out [4,256,128,128] f32
// out[b,c,2h+p,2w+q] = sum_{ki,kj} x[b,c,h+ki-2,w+kj-2] * kern[b,ki*5+kj,2h+p,2w+q]
//
// R9: single-variable test vs R8 = block->work mapping only. R8 (cc-fast) made
// concurrent blocks scatter 512B store chunks channel-major over 8MB/XCD ->
// suspected HBM row-buffer thrash on the dominant 64MB write stream (R8 ran at
// ~3.3 TB/s effective vs 6.4 TB/s fill-rate; occupancy & tiling already
// exonerated: R7 12 waves/CU == R8 24 waves/CU == ~30us). Here h is the fast
// block index: each XCD fills a contiguous 8MB output slice h-sequentially,
// holds a 2MB x slice in L2 (5x row reuse), streams kern[b] monotonically.
// Keep: 2col x 4ch regs tile, 25.6KB weight LDS, plain v4 stores (R6: NT 8B
// stores = 17x ECC-RMW catastrophe), XCD-chunked swizzle.

typedef float v2 __attribute__((ext_vector_type(2)));
typedef float v4 __attribute__((ext_vector_type(4)));

__global__ __launch_bounds__(256, 4)
void carafe_kernel(const float* __restrict__ x,
                   const float* __restrict__ kern,
                   float* __restrict__ out) {
    __shared__ __align__(16) float wt[25 * 256];   // [k][p][ow] for rows {2h,2h+1}

    // XCD-chunked swizzle: XCD k gets l in [256k, 256k+256) ascending (h-major).
    const int raw = blockIdx.x;
    const int l   = (raw & 7) * 256 + (raw >> 3);
    const int h   = l & 63;          // FAST: consecutive blocks = consecutive rows
    const int cc  = (l >> 6) & 7;    // 32-channel chunk (slow)
    const int b   = l >> 9;          // batch (slowest)
    const int tid = threadIdx.x;
    const int t   = tid & 31;        // col group: input cols 2t, 2t+1
    const int g   = tid >> 5;        // ch group: 4 channels
    const int c0  = cc * 32 + g * 4;

    // ---- stage weights (25.6KB), coalesced ----
    const float* kbase = kern + (size_t)b * 25 * 16384 + (size_t)(2 * h) * 128;
#pragma unroll
    for (int i = 0; i < 25; ++i)
        wt[i * 256 + tid] = kbase[(size_t)i * 16384 + tid];
    __syncthreads();

    float acc[4][2][2][2] = {};      // [ch][cj][p][q]
    const float* xb = x + (size_t)(b * 256 + c0) * 4096;

#pragma unroll
    for (int ki = 0; ki < 5; ++ki) {
        const int gr = h + ki - 2;
        if ((unsigned)gr >= 64u) continue;     // block-uniform zero-pad rows

        // x window per ch: cols 2t-2 .. 2t+3 via 3 aligned v2 loads
        float xw[4][6];
#pragma unroll
        for (int ch = 0; ch < 4; ++ch) {
            const float* rowp = xb + (size_t)ch * 4096 + gr * 64;
            const v2 A = *(const v2*)(rowp + (t ? 2 * t - 2 : 0));
            const v2 B = *(const v2*)(rowp + 2 * t);
            const v2 C = *(const v2*)(rowp + (t < 31 ? 2 * t + 2 : 60));
            xw[ch][0] = t ? A.x : 0.0f;            // col 2t-2
            xw[ch][1] = t ? A.y : 0.0f;            // col 2t-1
            xw[ch][2] = B.x;  xw[ch][3] = B.y;     // cols 2t, 2t+1
            xw[ch][4] = (t < 31) ? C.x : 0.0f;     // col 2t+2
            xw[ch][5] = (t < 31) ? C.y : 0.0f;     // col 2t+3
        }

#pragma unroll
        for (int kj = 0; kj < 5; ++kj) {
            const int k = ki * 5 + kj;
            const v4 w0 = *(const v4*)&wt[k * 256 + 4 * t];        // p=0, ow 4t..4t+3
            const v4 w1 = *(const v4*)&wt[k * 256 + 128 + 4 * t];  // p=1
#pragma unroll
            for (int ch = 0; ch < 4; ++ch) {
#pragma unroll
                for (int cj = 0; cj < 2; ++cj) {
                    const float xv = xw[ch][cj + kj];
                    acc[ch][cj][0][0] += w0[2 * cj]     * xv;
                    acc[ch][cj][0][1] += w0[2 * cj + 1] * xv;
                    acc[ch][cj][1][0] += w1[2 * cj]     * xv;
                    acc[ch][cj][1][1] += w1[2 * cj + 1] * xv;
                }
            }
        }
    }

    // ---- stores: 1 v4 per (ch,p); lanes t=0..31 cover a contiguous 512B row ----
#pragma unroll
    for (int ch = 0; ch < 4; ++ch) {
        float* ob = out + ((size_t)(b * 256 + c0 + ch) * 128 + 2 * h) * 128 + 4 * t;
#pragma unroll
        for (int p = 0; p < 2; ++p) {
            v4 s;
            s.x = acc[ch][0][p][0]; s.y = acc[ch][0][p][1];
            s.z = acc[ch][1][p][0]; s.w = acc[ch][1][p][1];
            *(v4*)(ob + p * 128) = s;
        }
    }
}

extern "C" void kernel_launch(void* const* d_in, const int* in_sizes, int n_in,
                              void* d_out, int out_size, void* d_ws, size_t ws_size,
                              hipStream_t stream) {
    const float* x    = (const float*)d_in[0];
    const float* kern = (const float*)d_in[1];
    float* out        = (float*)d_out;
    // grid: b(4) * cc(8) * h(64) = 2048 blocks of 256 threads
    carafe_kernel<<<dim3(2048), dim3(256), 0, stream>>>(x, kern, out);
}